// Round 11
// baseline (660.613 us; speedup 1.0000x reference)
//
#include <hip/hip_runtime.h>
#include <hip/hip_bf16.h>
#include <cstdint>
#include <cstddef>

#define NN 50000
#define NE 800000

typedef __bf16 bf16x8 __attribute__((ext_vector_type(8)));
typedef float  f32x4  __attribute__((ext_vector_type(4)));

// Pre-split, pre-transposed weights (hi/lo bf16 planes).
// W1t: [n][k] n<64,k<256 ; W2t: [n][k] n<128,k<64 ; Wd1t: [n][k] n<64,k<128.
__device__ __bf16 g_w1h[2][64 * 256];
__device__ __bf16 g_w1l[2][64 * 256];
__device__ __bf16 g_w2h[2][128 * 64];
__device__ __bf16 g_w2l[2][128 * 64];
__device__ __bf16 g_wd1h[64 * 128];
__device__ __bf16 g_wd1l[64 * 128];

__device__ __forceinline__ void split1(float v, __bf16& h, __bf16& l) {
    h = (__bf16)v;
    l = (__bf16)(v - (float)h);
}

// ---------------------------------------------------------------------------
// pre_kernel: blocks [0,224) split weights; blocks [224,224+3125) histogram
// ---------------------------------------------------------------------------
__global__ __launch_bounds__(256) void pre_kernel(
    const float* __restrict__ W1a, const float* __restrict__ W2a,
    const float* __restrict__ W1b, const float* __restrict__ W2b,
    const float* __restrict__ Wd1,
    const int* __restrict__ rcv, uint32_t* __restrict__ hist)
{
    const int b = blockIdx.x, t = threadIdx.x;
    if (b < 224) {
        int tid = b * 256 + t;
        if (tid < 16384) {                 // W1a [256][64] -> [64][256]
            int k = tid >> 6, n = tid & 63;
            __bf16 h, l; split1(W1a[tid], h, l);
            g_w1h[0][n * 256 + k] = h; g_w1l[0][n * 256 + k] = l;
        } else if (tid < 24576) {          // W2a [64][128] -> [128][64]
            int i = tid - 16384; int k = i >> 7, n = i & 127;
            __bf16 h, l; split1(W2a[i], h, l);
            g_w2h[0][n * 64 + k] = h; g_w2l[0][n * 64 + k] = l;
        } else if (tid < 40960) {          // W1b
            int i = tid - 24576; int k = i >> 6, n = i & 63;
            __bf16 h, l; split1(W1b[i], h, l);
            g_w1h[1][n * 256 + k] = h; g_w1l[1][n * 256 + k] = l;
        } else if (tid < 49152) {          // W2b
            int i = tid - 40960; int k = i >> 7, n = i & 127;
            __bf16 h, l; split1(W2b[i], h, l);
            g_w2h[1][n * 64 + k] = h; g_w2l[1][n * 64 + k] = l;
        } else if (tid < 57344) {          // Wd1 [128][64] -> [64][128]
            int i = tid - 49152; int k = i >> 6, n = i & 63;
            __bf16 h, l; split1(Wd1[i], h, l);
            g_wd1h[n * 128 + k] = h; g_wd1l[n * 128 + k] = l;
        }
    } else {
        int e = (b - 224) * 256 + t;
        if (e < NE) atomicAdd(hist + rcv[e], 1u);
    }
}

// ---------------------------------------------------------------------------
// scan chain for counting sort
// ---------------------------------------------------------------------------
__global__ void scan1_kernel(const uint32_t* __restrict__ hist,
                             uint32_t* __restrict__ pre, uint32_t* __restrict__ bsum) {
    __shared__ uint32_t s[256];
    int t = threadIdx.x;
    int i = blockIdx.x * 256 + t;
    uint32_t v = (i < NN) ? hist[i] : 0u;
    s[t] = v; __syncthreads();
    #pragma unroll
    for (int off = 1; off < 256; off <<= 1) {
        uint32_t tv = (t >= off) ? s[t - off] : 0u;
        __syncthreads();
        s[t] += tv; __syncthreads();
    }
    if (i < NN) pre[i] = s[t] - v;
    if (t == 255) bsum[blockIdx.x] = s[255];
}

__global__ void scan2_kernel(uint32_t* __restrict__ bsum, int nb) {
    __shared__ uint32_t s[256];
    int t = threadIdx.x;
    uint32_t v = (t < nb) ? bsum[t] : 0u;
    s[t] = v; __syncthreads();
    #pragma unroll
    for (int off = 1; off < 256; off <<= 1) {
        uint32_t tv = (t >= off) ? s[t - off] : 0u;
        __syncthreads();
        s[t] += tv; __syncthreads();
    }
    if (t < nb) bsum[t] = s[t] - v;
}

__global__ void scan3_kernel(const uint32_t* __restrict__ pre,
                             const uint32_t* __restrict__ bsum,
                             uint32_t* __restrict__ row_off) {
    int i = blockIdx.x * 256 + threadIdx.x;
    if (i < NN) row_off[i] = pre[i] + bsum[blockIdx.x];
    if (i == 0) row_off[NN] = NE;
}

// ---------------------------------------------------------------------------
// node_w1_body: per-node half-products of GEMM1.
//   hrp[n] = src[n] @ W1_top + b1 ; hsp[n] = src[n] @ W1_bot
// mean-mode (row_off != null): scale by 1/cnt and rezero seg.
// ---------------------------------------------------------------------------
__device__ __forceinline__ void node_w1_body(
    const float* __restrict__ src, const uint32_t* __restrict__ row_off,
    float* __restrict__ seg_rz, const float* __restrict__ b1,
    float* __restrict__ hrp, float* __restrict__ hsp, int layer, int blk)
{
    __shared__ __align__(16) __bf16 sAh[64 * 136];
    __shared__ __align__(16) __bf16 sAl[64 * 136];
    const int t = threadIdx.x;
    const int w = t >> 6, lane = t & 63, quad = lane >> 4, l16 = lane & 15;
    const int node0 = blk * 64;

    {
        const int r = t >> 2, kq = (t & 3) * 32;
        const int node = node0 + r;
        f32x4 v[8];
        if (node < NN) {
            const float* p = src + (size_t)node * 128 + kq;
            #pragma unroll
            for (int i = 0; i < 8; ++i) v[i] = *(const f32x4*)(p + 4 * i);
            if (row_off) {
                uint32_t c = row_off[node + 1] - row_off[node];
                float inv = (c > 0u) ? 1.0f / (float)c : 0.f;
                #pragma unroll
                for (int i = 0; i < 8; ++i) v[i] = v[i] * inv;
                float* z = seg_rz + (size_t)node * 128 + kq;
                #pragma unroll
                for (int i = 0; i < 8; ++i) *(f32x4*)(z + 4 * i) = (f32x4){0.f, 0.f, 0.f, 0.f};
            }
        } else {
            #pragma unroll
            for (int i = 0; i < 8; ++i) v[i] = (f32x4){0.f, 0.f, 0.f, 0.f};
        }
        bf16x8 hb[4], lb[4];
        #pragma unroll
        for (int i = 0; i < 8; ++i) {
            #pragma unroll
            for (int j = 0; j < 4; ++j) {
                __bf16 h, l; split1(v[i][j], h, l);
                hb[i >> 1][(i & 1) * 4 + j] = h;
                lb[i >> 1][(i & 1) * 4 + j] = l;
            }
        }
        __bf16* dh = sAh + r * 136 + kq;
        __bf16* dl = sAl + r * 136 + kq;
        #pragma unroll
        for (int i = 0; i < 4; ++i) {
            *(bf16x8*)(dh + 8 * i) = hb[i];
            *(bf16x8*)(dl + 8 * i) = lb[i];
        }
    }
    __syncthreads();

    const int n = 16 * w + l16;
    const __bf16* w1hp = g_w1h[layer] + n * 256;
    const __bf16* w1lp = g_w1l[layer] + n * 256;
    f32x4 acc[4][2] = {};
    #pragma unroll
    for (int kq = 0; kq < 4; ++kq) {
        const int k0 = kq * 32 + quad * 8;
        bf16x8 bh0 = *(const bf16x8*)(w1hp + k0);
        bf16x8 bl0 = *(const bf16x8*)(w1lp + k0);
        bf16x8 bh1 = *(const bf16x8*)(w1hp + 128 + k0);
        bf16x8 bl1 = *(const bf16x8*)(w1lp + 128 + k0);
        #pragma unroll
        for (int st = 0; st < 4; ++st) {
            bf16x8 ah = *(const bf16x8*)(sAh + (16 * st + l16) * 136 + k0);
            bf16x8 al = *(const bf16x8*)(sAl + (16 * st + l16) * 136 + k0);
            acc[st][0] = __builtin_amdgcn_mfma_f32_16x16x32_bf16(ah, bh0, acc[st][0], 0, 0, 0);
            acc[st][0] = __builtin_amdgcn_mfma_f32_16x16x32_bf16(al, bh0, acc[st][0], 0, 0, 0);
            acc[st][0] = __builtin_amdgcn_mfma_f32_16x16x32_bf16(ah, bl0, acc[st][0], 0, 0, 0);
            acc[st][1] = __builtin_amdgcn_mfma_f32_16x16x32_bf16(ah, bh1, acc[st][1], 0, 0, 0);
            acc[st][1] = __builtin_amdgcn_mfma_f32_16x16x32_bf16(al, bh1, acc[st][1], 0, 0, 0);
            acc[st][1] = __builtin_amdgcn_mfma_f32_16x16x32_bf16(ah, bl1, acc[st][1], 0, 0, 0);
        }
    }

    const float b1v = b1[n];
    #pragma unroll
    for (int st = 0; st < 4; ++st) {
        #pragma unroll
        for (int r = 0; r < 4; ++r) {
            const int node = node0 + 16 * st + quad * 4 + r;
            if (node < NN) {
                hrp[(size_t)node * 64 + n] = acc[st][0][r] + b1v;
                hsp[(size_t)node * 64 + n] = acc[st][1][r];
            }
        }
    }
}

// standalone node_w1 (layer-2 mean mode)
__global__ __launch_bounds__(256) void node_w1_kernel(
    const float* __restrict__ src, const uint32_t* __restrict__ row_off,
    float* __restrict__ seg_rz, const float* __restrict__ b1,
    float* __restrict__ hrp, float* __restrict__ hsp, int layer)
{
    node_w1_body(src, row_off, seg_rz, b1, hrp, hsp, layer, blockIdx.x);
}

// ---------------------------------------------------------------------------
// mid_kernel: blocks [0,nbn) = node_w1 layer-0; rest = rank-scatter building
// sorted (recv,send) pairs.
// ---------------------------------------------------------------------------
__global__ __launch_bounds__(256) void mid_kernel(
    const float* __restrict__ x, const float* __restrict__ b1a,
    float* __restrict__ hrp, float* __restrict__ hsp,
    const int* __restrict__ rcv, const int* __restrict__ snd,
    const uint32_t* __restrict__ row_off, uint32_t* __restrict__ cursor,
    int2* __restrict__ srt, int nbn)
{
    if ((int)blockIdx.x < nbn) {
        node_w1_body(x, (const uint32_t*)nullptr, (float*)nullptr, b1a, hrp, hsp, 0,
                     blockIdx.x);
    } else {
        int e = (blockIdx.x - nbn) * 256 + threadIdx.x;
        if (e < NE) {
            int r = rcv[e];
            uint32_t k = atomicAdd(cursor + r, 1u);
            srt[row_off[r] + k] = make_int2(r, snd[e]);
        }
    }
}

// ---------------------------------------------------------------------------
// seg_epilogue: exact segmented reduction over one sorted 16-edge strip.
// One atomic per receiver-run.
// ---------------------------------------------------------------------------
__device__ __forceinline__ void seg_epilogue(
    const f32x4* __restrict__ acc, const float* __restrict__ b2v,
    float* __restrict__ seg, int l16, int quad, int srcUp,
    int rc0, int rc1, int rc2, int rc3,
    float cL1, float cL2, float cL3, float cT0, float cT1, float cT2,
    bool m1, bool m2, bool m12same, bool whole, bool contNext,
    bool g1, bool g2, bool g3)
{
    #pragma unroll
    for (int ct = 0; ct < 8; ++ct) {
        const int n = 16 * ct + l16;
        const float bv = b2v[ct];
        const float v0 = fmaxf(acc[ct][0] + bv, 0.f);
        const float v1 = fmaxf(acc[ct][1] + bv, 0.f);
        const float v2 = fmaxf(acc[ct][2] + bv, 0.f);
        const float v3 = fmaxf(acc[ct][3] + bv, 0.f);

        float L = fmaf(cL3, v3, fmaf(cL2, v2, fmaf(cL1, v1, v0)));
        float T = fmaf(cT0, v0, fmaf(cT1, v1, fmaf(cT2, v2, v3)));

        if (m12same) {
            atomicAdd(seg + (size_t)rc1 * 128 + n, v1 + v2);
        } else {
            if (m1) atomicAdd(seg + (size_t)rc1 * 128 + n, v1);
            if (m2) atomicAdd(seg + (size_t)rc2 * 128 + n, v2);
        }

        float Tf = T, Lc = L;
        {
            float Tup = __shfl(Tf, srcUp);
            float add = g1 ? Tup : 0.f;
            if (whole) Tf += add; else Lc += add;
        }
        {
            float Tup = __shfl(Tf, srcUp);
            float add = g2 ? Tup : 0.f;
            if (whole) Tf += add; else Lc += add;
        }
        {
            float Tup = __shfl(Tf, srcUp);
            float add = g3 ? Tup : 0.f;
            if (whole) Tf += add; else Lc += add;
        }

        if (!whole)    atomicAdd(seg + (size_t)rc0 * 128 + n, Lc);
        if (!contNext) atomicAdd(seg + (size_t)rc3 * 128 + n, Tf);
    }
}

// ---------------------------------------------------------------------------
// edge_gemm2_kernel: 128 sorted edges/block, 4 waves; wave w owns TWO 16-edge
// strips and ALL 128 output cols. W2 staged in LDS with XOR-swizzled 16B
// chunks at stride 64 (no pad): chunk c of row r stored at c^(r&7). Same
// bank spread as the padded layout but LDS = 32768 B -> 5 blocks/CU.
// ---------------------------------------------------------------------------
__global__ __launch_bounds__(256, 5) void edge_gemm2_kernel(
    const float* __restrict__ hrp, const float* __restrict__ hsp,
    const int2* __restrict__ srt,
    const float* __restrict__ b2,
    float* __restrict__ seg, int layer)
{
    __shared__ __align__(16) __bf16 sWh[128 * 64];
    __shared__ __align__(16) __bf16 sWl[128 * 64];

    const int t = threadIdx.x;
    const int w = t >> 6, lane = t & 63, quad = lane >> 4, l16 = lane & 15;
    const int srcUp = (lane >= 16) ? lane - 16 : lane;
    const int srcDn = (lane < 48) ? lane + 16 : lane;

    // ---- stage W2 planes, swizzled (thread t -> row t>>1, half t&1) --------
    {
        const int r = t >> 1, hh = t & 1;
        const __bf16* sh = g_w2h[layer] + r * 64 + hh * 32;
        const __bf16* sl = g_w2l[layer] + r * 64 + hh * 32;
        __bf16* dh = sWh + r * 64;
        __bf16* dl = sWl + r * 64;
        const int rs = r & 7;
        #pragma unroll
        for (int i = 0; i < 4; ++i) {
            const int c = hh * 4 + i;           // source chunk index 0..7
            const int cs = c ^ rs;              // swizzled slot
            *(bf16x8*)(dh + cs * 8) = *(const bf16x8*)(sh + 8 * i);
            *(bf16x8*)(dl + cs * 8) = *(const bf16x8*)(sl + 8 * i);
        }
    }

    // ---- issue both strips' gathers (independent) --------------------------
    const int eA = blockIdx.x * 128 + w * 16;
    const int2 rsA = srt[eA + l16];
    const int2 rsB = srt[eA + 64 + l16];

    const float* hpA = hrp + (size_t)rsA.x * 64 + quad * 8;
    const float* spA = hsp + (size_t)rsA.y * 64 + quad * 8;
    const float* hpB = hrp + (size_t)rsB.x * 64 + quad * 8;
    const float* spB = hsp + (size_t)rsB.y * 64 + quad * 8;

    f32x4 ga0[4], gb0[4], ga1[4], gb1[4];
    ga0[0] = *(const f32x4*)(hpA);      ga0[1] = *(const f32x4*)(hpA + 4);
    ga0[2] = *(const f32x4*)(hpA + 32); ga0[3] = *(const f32x4*)(hpA + 36);
    gb0[0] = *(const f32x4*)(spA);      gb0[1] = *(const f32x4*)(spA + 4);
    gb0[2] = *(const f32x4*)(spA + 32); gb0[3] = *(const f32x4*)(spA + 36);
    ga1[0] = *(const f32x4*)(hpB);      ga1[1] = *(const f32x4*)(hpB + 4);
    ga1[2] = *(const f32x4*)(hpB + 32); ga1[3] = *(const f32x4*)(hpB + 36);
    gb1[0] = *(const f32x4*)(spB);      gb1[1] = *(const f32x4*)(spB + 4);
    gb1[2] = *(const f32x4*)(spB + 32); gb1[3] = *(const f32x4*)(spB + 36);

    float b2v[8];
    #pragma unroll
    for (int ct = 0; ct < 8; ++ct) b2v[ct] = b2[16 * ct + l16];

    // ---- pack A-fragments: h = relu(hrp+hsp), split hi/lo ------------------
    bf16x8 ahA[2], alA[2], ahB[2], alB[2];
    #pragma unroll
    for (int s = 0; s < 2; ++s) {
        #pragma unroll
        for (int hh = 0; hh < 2; ++hh) {
            f32x4 av = ga0[s * 2 + hh], bv = gb0[s * 2 + hh];
            f32x4 aw = ga1[s * 2 + hh], bw = gb1[s * 2 + hh];
            #pragma unroll
            for (int j = 0; j < 4; ++j) {
                float vA = fmaxf(av[j] + bv[j], 0.f);
                float vB = fmaxf(aw[j] + bw[j], 0.f);
                __bf16 h, l;
                split1(vA, h, l); ahA[s][hh * 4 + j] = h; alA[s][hh * 4 + j] = l;
                split1(vB, h, l); ahB[s][hh * 4 + j] = h; alB[s][hh * 4 + j] = l;
            }
        }
    }

    // ---- structural receiver masks per strip -------------------------------
    int rcA[4], rcB[4];
    #pragma unroll
    for (int r = 0; r < 4; ++r) {
        rcA[r] = __shfl(rsA.x, quad * 4 + r, 16);
        rcB[r] = __shfl(rsB.x, quad * 4 + r, 16);
    }

    const bool A10 = (rcA[1] == rcA[0]), A20 = (rcA[2] == rcA[0]);
    const bool A30 = (rcA[3] == rcA[0]), A23 = (rcA[2] == rcA[3]);
    const bool A13 = (rcA[1] == rcA[3]);
    const bool Awhole = A30;
    const int  ArUp = __shfl(rcA[3], srcUp);
    const int  ArDn = __shfl(rcA[0], srcDn);
    const bool AmatchUp  = (quad > 0) && (ArUp == rcA[0]);
    const bool AcontNext = (quad < 3) && (ArDn == rcA[3]);
    const bool Am1 = !A10 && !A13, Am2 = !A20 && !A23;
    const bool Am12 = Am1 && Am2 && (rcA[1] == rcA[2]);
    const float AcL1 = A10 ? 1.f : 0.f, AcL2 = A20 ? 1.f : 0.f, AcL3 = A30 ? 1.f : 0.f;
    const float AcT2 = A23 ? 1.f : 0.f, AcT1 = A13 ? 1.f : 0.f, AcT0 = A30 ? 1.f : 0.f;
    const bool Ag1 = AmatchUp && (quad == 1), Ag2 = AmatchUp && (quad == 2),
               Ag3 = AmatchUp && (quad == 3);

    const bool B10 = (rcB[1] == rcB[0]), B20 = (rcB[2] == rcB[0]);
    const bool B30 = (rcB[3] == rcB[0]), B23 = (rcB[2] == rcB[3]);
    const bool B13 = (rcB[1] == rcB[3]);
    const bool Bwhole = B30;
    const int  BrUp = __shfl(rcB[3], srcUp);
    const int  BrDn = __shfl(rcB[0], srcDn);
    const bool BmatchUp  = (quad > 0) && (BrUp == rcB[0]);
    const bool BcontNext = (quad < 3) && (BrDn == rcB[3]);
    const bool Bm1 = !B10 && !B13, Bm2 = !B20 && !B23;
    const bool Bm12 = Bm1 && Bm2 && (rcB[1] == rcB[2]);
    const float BcL1 = B10 ? 1.f : 0.f, BcL2 = B20 ? 1.f : 0.f, BcL3 = B30 ? 1.f : 0.f;
    const float BcT2 = B23 ? 1.f : 0.f, BcT1 = B13 ? 1.f : 0.f, BcT0 = B30 ? 1.f : 0.f;
    const bool Bg1 = BmatchUp && (quad == 1), Bg2 = BmatchUp && (quad == 2),
               Bg3 = BmatchUp && (quad == 3);

    __syncthreads();   // weights staged

    // ---- strip A: GEMM2 + epilogue -----------------------------------------
    {
        f32x4 acc[8] = {};
        #pragma unroll
        for (int ct = 0; ct < 8; ++ct) {
            const int r = 16 * ct + l16;
            const int rs = r & 7;
            #pragma unroll
            for (int s = 0; s < 2; ++s) {
                const int cs = (s * 4 + quad) ^ rs;
                bf16x8 bh = *(const bf16x8*)(sWh + r * 64 + cs * 8);
                bf16x8 bl = *(const bf16x8*)(sWl + r * 64 + cs * 8);
                acc[ct] = __builtin_amdgcn_mfma_f32_16x16x32_bf16(ahA[s], bh, acc[ct], 0, 0, 0);
                acc[ct] = __builtin_amdgcn_mfma_f32_16x16x32_bf16(alA[s], bh, acc[ct], 0, 0, 0);
                acc[ct] = __builtin_amdgcn_mfma_f32_16x16x32_bf16(ahA[s], bl, acc[ct], 0, 0, 0);
            }
        }
        seg_epilogue(acc, b2v, seg, l16, quad, srcUp,
                     rcA[0], rcA[1], rcA[2], rcA[3],
                     AcL1, AcL2, AcL3, AcT0, AcT1, AcT2,
                     Am1, Am2, Am12, Awhole, AcontNext, Ag1, Ag2, Ag3);
    }

    // ---- strip B: GEMM2 + epilogue -----------------------------------------
    {
        f32x4 acc[8] = {};
        #pragma unroll
        for (int ct = 0; ct < 8; ++ct) {
            const int r = 16 * ct + l16;
            const int rs = r & 7;
            #pragma unroll
            for (int s = 0; s < 2; ++s) {
                const int cs = (s * 4 + quad) ^ rs;
                bf16x8 bh = *(const bf16x8*)(sWh + r * 64 + cs * 8);
                bf16x8 bl = *(const bf16x8*)(sWl + r * 64 + cs * 8);
                acc[ct] = __builtin_amdgcn_mfma_f32_16x16x32_bf16(ahB[s], bh, acc[ct], 0, 0, 0);
                acc[ct] = __builtin_amdgcn_mfma_f32_16x16x32_bf16(alB[s], bh, acc[ct], 0, 0, 0);
                acc[ct] = __builtin_amdgcn_mfma_f32_16x16x32_bf16(ahB[s], bl, acc[ct], 0, 0, 0);
            }
        }
        seg_epilogue(acc, b2v, seg, l16, quad, srcUp,
                     rcB[0], rcB[1], rcB[2], rcB[3],
                     BcL1, BcL2, BcL3, BcT0, BcT1, BcT2,
                     Bm1, Bm2, Bm12, Bwhole, BcontNext, Bg1, Bg2, Bg3);
    }
}

// ---------------------------------------------------------------------------
// tail_kernel: per node: m = seg/cnt ; out = relu(m @ Wd1 + bd1) @ Wd2 + bd2
// ---------------------------------------------------------------------------
__global__ __launch_bounds__(256) void tail_kernel(
    const float* __restrict__ seg, const uint32_t* __restrict__ row_off,
    const float* __restrict__ bd1, const float* __restrict__ Wd2,
    const float* __restrict__ bd2, float* __restrict__ out)
{
    __shared__ __align__(16) __bf16 sAh[64 * 136];
    __shared__ __align__(16) __bf16 sAl[64 * 136];
    __shared__ float sOut[64];
    const int t = threadIdx.x;
    const int w = t >> 6, lane = t & 63, quad = lane >> 4, l16 = lane & 15;
    const int node0 = blockIdx.x * 64;

    if (t < 64) sOut[t] = 0.f;

    {
        const int r = t >> 2, kq = (t & 3) * 32;
        const int node = node0 + r;
        f32x4 v[8];
        if (node < NN) {
            uint32_t c = row_off[node + 1] - row_off[node];
            float inv = (c > 0u) ? 1.0f / (float)c : 0.f;
            const float* p = seg + (size_t)node * 128 + kq;
            #pragma unroll
            for (int i = 0; i < 8; ++i) v[i] = *(const f32x4*)(p + 4 * i) * inv;
        } else {
            #pragma unroll
            for (int i = 0; i < 8; ++i) v[i] = (f32x4){0.f, 0.f, 0.f, 0.f};
        }
        bf16x8 hb[4], lb[4];
        #pragma unroll
        for (int i = 0; i < 8; ++i) {
            #pragma unroll
            for (int j = 0; j < 4; ++j) {
                __bf16 h, l; split1(v[i][j], h, l);
                hb[i >> 1][(i & 1) * 4 + j] = h;
                lb[i >> 1][(i & 1) * 4 + j] = l;
            }
        }
        __bf16* dh = sAh + r * 136 + kq;
        __bf16* dl = sAl + r * 136 + kq;
        #pragma unroll
        for (int i = 0; i < 4; ++i) {
            *(bf16x8*)(dh + 8 * i) = hb[i];
            *(bf16x8*)(dl + 8 * i) = lb[i];
        }
    }
    __syncthreads();

    const int n = 16 * w + l16;
    const __bf16* bhp = g_wd1h + n * 128;
    const __bf16* blp = g_wd1l + n * 128;
    f32x4 acc[4] = {};
    #pragma unroll
    for (int kq = 0; kq < 4; ++kq) {
        const int k0 = kq * 32 + quad * 8;
        bf16x8 bh = *(const bf16x8*)(bhp + k0);
        bf16x8 bl = *(const bf16x8*)(blp + k0);
        #pragma unroll
        for (int st = 0; st < 4; ++st) {
            bf16x8 ah = *(const bf16x8*)(sAh + (16 * st + l16) * 136 + k0);
            bf16x8 al = *(const bf16x8*)(sAl + (16 * st + l16) * 136 + k0);
            acc[st] = __builtin_amdgcn_mfma_f32_16x16x32_bf16(ah, bh, acc[st], 0, 0, 0);
            acc[st] = __builtin_amdgcn_mfma_f32_16x16x32_bf16(al, bh, acc[st], 0, 0, 0);
            acc[st] = __builtin_amdgcn_mfma_f32_16x16x32_bf16(ah, bl, acc[st], 0, 0, 0);
        }
    }

    const float bd1v = bd1[n];
    const float wd2v = Wd2[n];
    #pragma unroll
    for (int st = 0; st < 4; ++st) {
        #pragma unroll
        for (int r = 0; r < 4; ++r) {
            float p = fmaxf(acc[st][r] + bd1v, 0.f) * wd2v;
            p += __shfl_xor(p, 1, 16);
            p += __shfl_xor(p, 2, 16);
            p += __shfl_xor(p, 4, 16);
            p += __shfl_xor(p, 8, 16);
            if (l16 == 0) atomicAdd(&sOut[16 * st + quad * 4 + r], p);
        }
    }
    __syncthreads();
    if (t < 64) {
        const int node = node0 + t;
        if (node < NN) out[node] = sOut[t] + bd2[0];
    }
}

// ---------------------------------------------------------------------------
extern "C" void kernel_launch(void* const* d_in, const int* in_sizes, int n_in,
                              void* d_out, int out_size, void* d_ws, size_t ws_size,
                              hipStream_t stream) {
    const float* x   = (const float*)d_in[0];
    const int*   snd = (const int*)  d_in[1];
    const int*   rcv = (const int*)  d_in[2];
    const float* W1a = (const float*)d_in[3];
    const float* b1a = (const float*)d_in[4];
    const float* W2a = (const float*)d_in[5];
    const float* b2a = (const float*)d_in[6];
    const float* W1b = (const float*)d_in[7];
    const float* b1b = (const float*)d_in[8];
    const float* W2b = (const float*)d_in[9];
    const float* b2b = (const float*)d_in[10];
    const float* Wd1 = (const float*)d_in[11];
    const float* bd1 = (const float*)d_in[12];
    const float* Wd2 = (const float*)d_in[13];
    const float* bd2 = (const float*)d_in[14];
    float* out = (float*)d_out;

    // ws layout: seg [NN*128 f32] | hist [NN] | cursor [NN] | row_off [NN+1] |
    //            pre [NN] | bsum [256] | srt [NE int2] | hrp [NN*64] | hsp [NN*64]
    float*    seg     = (float*)d_ws;
    uint32_t* hist    = (uint32_t*)(seg + (size_t)NN * 128);
    uint32_t* cursor  = hist + NN;
    uint32_t* row_off = cursor + NN;
    uint32_t* pre     = row_off + (NN + 1);
    uint32_t* bsum    = pre + NN;
    int2*     srt     = (int2*)(bsum + 256);
    float*    hrp     = (float*)(srt + NE);
    float*    hsp     = hrp + (size_t)NN * 64;

    hipMemsetAsync(seg, 0, ((size_t)NN * 128 + 2 * NN) * sizeof(float), stream);

    const int nb  = (NN + 255) / 256;   // 196
    const int nbn = (NN + 63) / 64;     // 782
    const int neb = (NE + 255) / 256;   // 3125

    hipLaunchKernelGGL(pre_kernel, dim3(224 + neb), dim3(256), 0, stream,
                       W1a, W2a, W1b, W2b, Wd1, rcv, hist);
    hipLaunchKernelGGL(scan1_kernel, dim3(nb), dim3(256), 0, stream, hist, pre, bsum);
    hipLaunchKernelGGL(scan2_kernel, dim3(1), dim3(256), 0, stream, bsum, nb);
    hipLaunchKernelGGL(scan3_kernel, dim3(nb), dim3(256), 0, stream, pre, bsum, row_off);
    hipLaunchKernelGGL(mid_kernel, dim3(nbn + neb), dim3(256), 0, stream,
                       x, b1a, hrp, hsp, rcv, snd, row_off, cursor, srt, nbn);

    // layer 1 edges
    hipLaunchKernelGGL(edge_gemm2_kernel, dim3(NE / 128), dim3(256), 0, stream,
                       hrp, hsp, srt, b2a, seg, 0);
    // layer 2 node half-products (mean-mode; rezeros seg)
    hipLaunchKernelGGL(node_w1_kernel, dim3(nbn), dim3(256), 0, stream,
                       seg, row_off, seg, b1b, hrp, hsp, 1);
    // layer 2 edges
    hipLaunchKernelGGL(edge_gemm2_kernel, dim3(NE / 128), dim3(256), 0, stream,
                       hrp, hsp, srt, b2b, seg, 1);
    // dense tail
    hipLaunchKernelGGL(tail_kernel, dim3(nbn), dim3(256), 0, stream,
                       seg, row_off, bd1, Wd2, bd2, out);
}

// Round 12
// 399.642 us; speedup vs baseline: 1.6530x; 1.6530x over previous
//
#include <hip/hip_runtime.h>
#include <hip/hip_bf16.h>
#include <cstdint>
#include <cstddef>

#define NN 50000
#define NE 800000

typedef __bf16 bf16x8 __attribute__((ext_vector_type(8)));
typedef float  f32x4  __attribute__((ext_vector_type(4)));

// Pre-split, pre-transposed weights (hi/lo bf16 planes).
// W1t: [n][k] n<64,k<256 ; W2t: [n][k] n<128,k<64 ; Wd1t: [n][k] n<64,k<128.
__device__ __bf16 g_w1h[2][64 * 256];
__device__ __bf16 g_w1l[2][64 * 256];
__device__ __bf16 g_w2h[2][128 * 64];
__device__ __bf16 g_w2l[2][128 * 64];
__device__ __bf16 g_wd1h[64 * 128];
__device__ __bf16 g_wd1l[64 * 128];

__device__ __forceinline__ void split1(float v, __bf16& h, __bf16& l) {
    h = (__bf16)v;
    l = (__bf16)(v - (float)h);
}

// ---------------------------------------------------------------------------
// pre_kernel: blocks [0,224) split weights; blocks [224,224+3125) histogram
// ---------------------------------------------------------------------------
__global__ __launch_bounds__(256) void pre_kernel(
    const float* __restrict__ W1a, const float* __restrict__ W2a,
    const float* __restrict__ W1b, const float* __restrict__ W2b,
    const float* __restrict__ Wd1,
    const int* __restrict__ rcv, uint32_t* __restrict__ hist)
{
    const int b = blockIdx.x, t = threadIdx.x;
    if (b < 224) {
        int tid = b * 256 + t;
        if (tid < 16384) {                 // W1a [256][64] -> [64][256]
            int k = tid >> 6, n = tid & 63;
            __bf16 h, l; split1(W1a[tid], h, l);
            g_w1h[0][n * 256 + k] = h; g_w1l[0][n * 256 + k] = l;
        } else if (tid < 24576) {          // W2a [64][128] -> [128][64]
            int i = tid - 16384; int k = i >> 7, n = i & 127;
            __bf16 h, l; split1(W2a[i], h, l);
            g_w2h[0][n * 64 + k] = h; g_w2l[0][n * 64 + k] = l;
        } else if (tid < 40960) {          // W1b
            int i = tid - 24576; int k = i >> 6, n = i & 63;
            __bf16 h, l; split1(W1b[i], h, l);
            g_w1h[1][n * 256 + k] = h; g_w1l[1][n * 256 + k] = l;
        } else if (tid < 49152) {          // W2b
            int i = tid - 40960; int k = i >> 7, n = i & 127;
            __bf16 h, l; split1(W2b[i], h, l);
            g_w2h[1][n * 64 + k] = h; g_w2l[1][n * 64 + k] = l;
        } else if (tid < 57344) {          // Wd1 [128][64] -> [64][128]
            int i = tid - 49152; int k = i >> 6, n = i & 63;
            __bf16 h, l; split1(Wd1[i], h, l);
            g_wd1h[n * 128 + k] = h; g_wd1l[n * 128 + k] = l;
        }
    } else {
        int e = (b - 224) * 256 + t;
        if (e < NE) atomicAdd(hist + rcv[e], 1u);
    }
}

// ---------------------------------------------------------------------------
// scan chain for counting sort
// ---------------------------------------------------------------------------
__global__ void scan1_kernel(const uint32_t* __restrict__ hist,
                             uint32_t* __restrict__ pre, uint32_t* __restrict__ bsum) {
    __shared__ uint32_t s[256];
    int t = threadIdx.x;
    int i = blockIdx.x * 256 + t;
    uint32_t v = (i < NN) ? hist[i] : 0u;
    s[t] = v; __syncthreads();
    #pragma unroll
    for (int off = 1; off < 256; off <<= 1) {
        uint32_t tv = (t >= off) ? s[t - off] : 0u;
        __syncthreads();
        s[t] += tv; __syncthreads();
    }
    if (i < NN) pre[i] = s[t] - v;
    if (t == 255) bsum[blockIdx.x] = s[255];
}

__global__ void scan2_kernel(uint32_t* __restrict__ bsum, int nb) {
    __shared__ uint32_t s[256];
    int t = threadIdx.x;
    uint32_t v = (t < nb) ? bsum[t] : 0u;
    s[t] = v; __syncthreads();
    #pragma unroll
    for (int off = 1; off < 256; off <<= 1) {
        uint32_t tv = (t >= off) ? s[t - off] : 0u;
        __syncthreads();
        s[t] += tv; __syncthreads();
    }
    if (t < nb) bsum[t] = s[t] - v;
}

__global__ void scan3_kernel(const uint32_t* __restrict__ pre,
                             const uint32_t* __restrict__ bsum,
                             uint32_t* __restrict__ row_off) {
    int i = blockIdx.x * 256 + threadIdx.x;
    if (i < NN) row_off[i] = pre[i] + bsum[blockIdx.x];
    if (i == 0) row_off[NN] = NE;
}

// ---------------------------------------------------------------------------
// node_w1_body: per-node half-products of GEMM1.
//   hrp[n] = src[n] @ W1_top + b1 ; hsp[n] = src[n] @ W1_bot
// mean-mode (row_off != null): scale by 1/cnt and rezero seg.
// ---------------------------------------------------------------------------
__device__ __forceinline__ void node_w1_body(
    const float* __restrict__ src, const uint32_t* __restrict__ row_off,
    float* __restrict__ seg_rz, const float* __restrict__ b1,
    float* __restrict__ hrp, float* __restrict__ hsp, int layer, int blk)
{
    __shared__ __align__(16) __bf16 sAh[64 * 136];
    __shared__ __align__(16) __bf16 sAl[64 * 136];
    const int t = threadIdx.x;
    const int w = t >> 6, lane = t & 63, quad = lane >> 4, l16 = lane & 15;
    const int node0 = blk * 64;

    {
        const int r = t >> 2, kq = (t & 3) * 32;
        const int node = node0 + r;
        f32x4 v[8];
        if (node < NN) {
            const float* p = src + (size_t)node * 128 + kq;
            #pragma unroll
            for (int i = 0; i < 8; ++i) v[i] = *(const f32x4*)(p + 4 * i);
            if (row_off) {
                uint32_t c = row_off[node + 1] - row_off[node];
                float inv = (c > 0u) ? 1.0f / (float)c : 0.f;
                #pragma unroll
                for (int i = 0; i < 8; ++i) v[i] = v[i] * inv;
                float* z = seg_rz + (size_t)node * 128 + kq;
                #pragma unroll
                for (int i = 0; i < 8; ++i) *(f32x4*)(z + 4 * i) = (f32x4){0.f, 0.f, 0.f, 0.f};
            }
        } else {
            #pragma unroll
            for (int i = 0; i < 8; ++i) v[i] = (f32x4){0.f, 0.f, 0.f, 0.f};
        }
        bf16x8 hb[4], lb[4];
        #pragma unroll
        for (int i = 0; i < 8; ++i) {
            #pragma unroll
            for (int j = 0; j < 4; ++j) {
                __bf16 h, l; split1(v[i][j], h, l);
                hb[i >> 1][(i & 1) * 4 + j] = h;
                lb[i >> 1][(i & 1) * 4 + j] = l;
            }
        }
        __bf16* dh = sAh + r * 136 + kq;
        __bf16* dl = sAl + r * 136 + kq;
        #pragma unroll
        for (int i = 0; i < 4; ++i) {
            *(bf16x8*)(dh + 8 * i) = hb[i];
            *(bf16x8*)(dl + 8 * i) = lb[i];
        }
    }
    __syncthreads();

    const int n = 16 * w + l16;
    const __bf16* w1hp = g_w1h[layer] + n * 256;
    const __bf16* w1lp = g_w1l[layer] + n * 256;
    f32x4 acc[4][2] = {};
    #pragma unroll
    for (int kq = 0; kq < 4; ++kq) {
        const int k0 = kq * 32 + quad * 8;
        bf16x8 bh0 = *(const bf16x8*)(w1hp + k0);
        bf16x8 bl0 = *(const bf16x8*)(w1lp + k0);
        bf16x8 bh1 = *(const bf16x8*)(w1hp + 128 + k0);
        bf16x8 bl1 = *(const bf16x8*)(w1lp + 128 + k0);
        #pragma unroll
        for (int st = 0; st < 4; ++st) {
            bf16x8 ah = *(const bf16x8*)(sAh + (16 * st + l16) * 136 + k0);
            bf16x8 al = *(const bf16x8*)(sAl + (16 * st + l16) * 136 + k0);
            acc[st][0] = __builtin_amdgcn_mfma_f32_16x16x32_bf16(ah, bh0, acc[st][0], 0, 0, 0);
            acc[st][0] = __builtin_amdgcn_mfma_f32_16x16x32_bf16(al, bh0, acc[st][0], 0, 0, 0);
            acc[st][0] = __builtin_amdgcn_mfma_f32_16x16x32_bf16(ah, bl0, acc[st][0], 0, 0, 0);
            acc[st][1] = __builtin_amdgcn_mfma_f32_16x16x32_bf16(ah, bh1, acc[st][1], 0, 0, 0);
            acc[st][1] = __builtin_amdgcn_mfma_f32_16x16x32_bf16(al, bh1, acc[st][1], 0, 0, 0);
            acc[st][1] = __builtin_amdgcn_mfma_f32_16x16x32_bf16(ah, bl1, acc[st][1], 0, 0, 0);
        }
    }

    const float b1v = b1[n];
    #pragma unroll
    for (int st = 0; st < 4; ++st) {
        #pragma unroll
        for (int r = 0; r < 4; ++r) {
            const int node = node0 + 16 * st + quad * 4 + r;
            if (node < NN) {
                hrp[(size_t)node * 64 + n] = acc[st][0][r] + b1v;
                hsp[(size_t)node * 64 + n] = acc[st][1][r];
            }
        }
    }
}

// standalone node_w1 (layer-2 mean mode)
__global__ __launch_bounds__(256) void node_w1_kernel(
    const float* __restrict__ src, const uint32_t* __restrict__ row_off,
    float* __restrict__ seg_rz, const float* __restrict__ b1,
    float* __restrict__ hrp, float* __restrict__ hsp, int layer)
{
    node_w1_body(src, row_off, seg_rz, b1, hrp, hsp, layer, blockIdx.x);
}

// ---------------------------------------------------------------------------
// mid_kernel: blocks [0,nbn) = node_w1 layer-0; rest = rank-scatter building
// sorted (recv,send) pairs.
// ---------------------------------------------------------------------------
__global__ __launch_bounds__(256) void mid_kernel(
    const float* __restrict__ x, const float* __restrict__ b1a,
    float* __restrict__ hrp, float* __restrict__ hsp,
    const int* __restrict__ rcv, const int* __restrict__ snd,
    const uint32_t* __restrict__ row_off, uint32_t* __restrict__ cursor,
    int2* __restrict__ srt, int nbn)
{
    if ((int)blockIdx.x < nbn) {
        node_w1_body(x, (const uint32_t*)nullptr, (float*)nullptr, b1a, hrp, hsp, 0,
                     blockIdx.x);
    } else {
        int e = (blockIdx.x - nbn) * 256 + threadIdx.x;
        if (e < NE) {
            int r = rcv[e];
            uint32_t k = atomicAdd(cursor + r, 1u);
            srt[row_off[r] + k] = make_int2(r, snd[e]);
        }
    }
}

// ---------------------------------------------------------------------------
// seg_epilogue: exact segmented reduction over one sorted 16-edge strip.
// One atomic per receiver-run.
// ---------------------------------------------------------------------------
__device__ __forceinline__ void seg_epilogue(
    const f32x4* __restrict__ acc, const float* __restrict__ b2v,
    float* __restrict__ seg, int l16, int quad, int srcUp,
    int rc0, int rc1, int rc2, int rc3,
    float cL1, float cL2, float cL3, float cT0, float cT1, float cT2,
    bool m1, bool m2, bool m12same, bool whole, bool contNext,
    bool g1, bool g2, bool g3)
{
    #pragma unroll
    for (int ct = 0; ct < 8; ++ct) {
        const int n = 16 * ct + l16;
        const float bv = b2v[ct];
        const float v0 = fmaxf(acc[ct][0] + bv, 0.f);
        const float v1 = fmaxf(acc[ct][1] + bv, 0.f);
        const float v2 = fmaxf(acc[ct][2] + bv, 0.f);
        const float v3 = fmaxf(acc[ct][3] + bv, 0.f);

        float L = fmaf(cL3, v3, fmaf(cL2, v2, fmaf(cL1, v1, v0)));
        float T = fmaf(cT0, v0, fmaf(cT1, v1, fmaf(cT2, v2, v3)));

        if (m12same) {
            atomicAdd(seg + (size_t)rc1 * 128 + n, v1 + v2);
        } else {
            if (m1) atomicAdd(seg + (size_t)rc1 * 128 + n, v1);
            if (m2) atomicAdd(seg + (size_t)rc2 * 128 + n, v2);
        }

        float Tf = T, Lc = L;
        {
            float Tup = __shfl(Tf, srcUp);
            float add = g1 ? Tup : 0.f;
            if (whole) Tf += add; else Lc += add;
        }
        {
            float Tup = __shfl(Tf, srcUp);
            float add = g2 ? Tup : 0.f;
            if (whole) Tf += add; else Lc += add;
        }
        {
            float Tup = __shfl(Tf, srcUp);
            float add = g3 ? Tup : 0.f;
            if (whole) Tf += add; else Lc += add;
        }

        if (!whole)    atomicAdd(seg + (size_t)rc0 * 128 + n, Lc);
        if (!contNext) atomicAdd(seg + (size_t)rc3 * 128 + n, Tf);
    }
}

// ---------------------------------------------------------------------------
// edge_gemm2_kernel: 128 sorted edges/block, 4 waves; wave w owns TWO 16-edge
// strips and ALL 128 output cols. W2 staged in LDS with XOR-swizzled 16B
// chunks at stride 64 (no pad): chunk c of row r stored at c^(r&7).
// LDS = 32768 B -> 5 blocks/CU (LDS-limited); plain launch_bounds so the
// allocator keeps ~68 VGPR (NO min-waves coercion -- round 11's forced
// (256,5) squeezed VGPR to 48 and spilled to scratch: WRITE 48->554 MB).
// ---------------------------------------------------------------------------
__global__ __launch_bounds__(256) void edge_gemm2_kernel(
    const float* __restrict__ hrp, const float* __restrict__ hsp,
    const int2* __restrict__ srt,
    const float* __restrict__ b2,
    float* __restrict__ seg, int layer)
{
    __shared__ __align__(16) __bf16 sWh[128 * 64];
    __shared__ __align__(16) __bf16 sWl[128 * 64];

    const int t = threadIdx.x;
    const int w = t >> 6, lane = t & 63, quad = lane >> 4, l16 = lane & 15;
    const int srcUp = (lane >= 16) ? lane - 16 : lane;
    const int srcDn = (lane < 48) ? lane + 16 : lane;

    // ---- stage W2 planes, swizzled (thread t -> row t>>1, half t&1) --------
    {
        const int r = t >> 1, hh = t & 1;
        const __bf16* sh = g_w2h[layer] + r * 64 + hh * 32;
        const __bf16* sl = g_w2l[layer] + r * 64 + hh * 32;
        __bf16* dh = sWh + r * 64;
        __bf16* dl = sWl + r * 64;
        const int rs = r & 7;
        #pragma unroll
        for (int i = 0; i < 4; ++i) {
            const int c = hh * 4 + i;           // source chunk index 0..7
            const int cs = c ^ rs;              // swizzled slot
            *(bf16x8*)(dh + cs * 8) = *(const bf16x8*)(sh + 8 * i);
            *(bf16x8*)(dl + cs * 8) = *(const bf16x8*)(sl + 8 * i);
        }
    }

    // ---- issue both strips' gathers (independent) --------------------------
    const int eA = blockIdx.x * 128 + w * 16;
    const int2 rsA = srt[eA + l16];
    const int2 rsB = srt[eA + 64 + l16];

    const float* hpA = hrp + (size_t)rsA.x * 64 + quad * 8;
    const float* spA = hsp + (size_t)rsA.y * 64 + quad * 8;
    const float* hpB = hrp + (size_t)rsB.x * 64 + quad * 8;
    const float* spB = hsp + (size_t)rsB.y * 64 + quad * 8;

    f32x4 ga0[4], gb0[4], ga1[4], gb1[4];
    ga0[0] = *(const f32x4*)(hpA);      ga0[1] = *(const f32x4*)(hpA + 4);
    ga0[2] = *(const f32x4*)(hpA + 32); ga0[3] = *(const f32x4*)(hpA + 36);
    gb0[0] = *(const f32x4*)(spA);      gb0[1] = *(const f32x4*)(spA + 4);
    gb0[2] = *(const f32x4*)(spA + 32); gb0[3] = *(const f32x4*)(spA + 36);
    ga1[0] = *(const f32x4*)(hpB);      ga1[1] = *(const f32x4*)(hpB + 4);
    ga1[2] = *(const f32x4*)(hpB + 32); ga1[3] = *(const f32x4*)(hpB + 36);
    gb1[0] = *(const f32x4*)(spB);      gb1[1] = *(const f32x4*)(spB + 4);
    gb1[2] = *(const f32x4*)(spB + 32); gb1[3] = *(const f32x4*)(spB + 36);

    float b2v[8];
    #pragma unroll
    for (int ct = 0; ct < 8; ++ct) b2v[ct] = b2[16 * ct + l16];

    // ---- pack A-fragments: h = relu(hrp+hsp), split hi/lo ------------------
    bf16x8 ahA[2], alA[2], ahB[2], alB[2];
    #pragma unroll
    for (int s = 0; s < 2; ++s) {
        #pragma unroll
        for (int hh = 0; hh < 2; ++hh) {
            f32x4 av = ga0[s * 2 + hh], bv = gb0[s * 2 + hh];
            f32x4 aw = ga1[s * 2 + hh], bw = gb1[s * 2 + hh];
            #pragma unroll
            for (int j = 0; j < 4; ++j) {
                float vA = fmaxf(av[j] + bv[j], 0.f);
                float vB = fmaxf(aw[j] + bw[j], 0.f);
                __bf16 h, l;
                split1(vA, h, l); ahA[s][hh * 4 + j] = h; alA[s][hh * 4 + j] = l;
                split1(vB, h, l); ahB[s][hh * 4 + j] = h; alB[s][hh * 4 + j] = l;
            }
        }
    }

    // ---- structural receiver masks per strip -------------------------------
    int rcA[4], rcB[4];
    #pragma unroll
    for (int r = 0; r < 4; ++r) {
        rcA[r] = __shfl(rsA.x, quad * 4 + r, 16);
        rcB[r] = __shfl(rsB.x, quad * 4 + r, 16);
    }

    const bool A10 = (rcA[1] == rcA[0]), A20 = (rcA[2] == rcA[0]);
    const bool A30 = (rcA[3] == rcA[0]), A23 = (rcA[2] == rcA[3]);
    const bool A13 = (rcA[1] == rcA[3]);
    const bool Awhole = A30;
    const int  ArUp = __shfl(rcA[3], srcUp);
    const int  ArDn = __shfl(rcA[0], srcDn);
    const bool AmatchUp  = (quad > 0) && (ArUp == rcA[0]);
    const bool AcontNext = (quad < 3) && (ArDn == rcA[3]);
    const bool Am1 = !A10 && !A13, Am2 = !A20 && !A23;
    const bool Am12 = Am1 && Am2 && (rcA[1] == rcA[2]);
    const float AcL1 = A10 ? 1.f : 0.f, AcL2 = A20 ? 1.f : 0.f, AcL3 = A30 ? 1.f : 0.f;
    const float AcT2 = A23 ? 1.f : 0.f, AcT1 = A13 ? 1.f : 0.f, AcT0 = A30 ? 1.f : 0.f;
    const bool Ag1 = AmatchUp && (quad == 1), Ag2 = AmatchUp && (quad == 2),
               Ag3 = AmatchUp && (quad == 3);

    const bool B10 = (rcB[1] == rcB[0]), B20 = (rcB[2] == rcB[0]);
    const bool B30 = (rcB[3] == rcB[0]), B23 = (rcB[2] == rcB[3]);
    const bool B13 = (rcB[1] == rcB[3]);
    const bool Bwhole = B30;
    const int  BrUp = __shfl(rcB[3], srcUp);
    const int  BrDn = __shfl(rcB[0], srcDn);
    const bool BmatchUp  = (quad > 0) && (BrUp == rcB[0]);
    const bool BcontNext = (quad < 3) && (BrDn == rcB[3]);
    const bool Bm1 = !B10 && !B13, Bm2 = !B20 && !B23;
    const bool Bm12 = Bm1 && Bm2 && (rcB[1] == rcB[2]);
    const float BcL1 = B10 ? 1.f : 0.f, BcL2 = B20 ? 1.f : 0.f, BcL3 = B30 ? 1.f : 0.f;
    const float BcT2 = B23 ? 1.f : 0.f, BcT1 = B13 ? 1.f : 0.f, BcT0 = B30 ? 1.f : 0.f;
    const bool Bg1 = BmatchUp && (quad == 1), Bg2 = BmatchUp && (quad == 2),
               Bg3 = BmatchUp && (quad == 3);

    __syncthreads();   // weights staged

    // ---- strip A: GEMM2 + epilogue -----------------------------------------
    {
        f32x4 acc[8] = {};
        #pragma unroll
        for (int ct = 0; ct < 8; ++ct) {
            const int r = 16 * ct + l16;
            const int rs = r & 7;
            #pragma unroll
            for (int s = 0; s < 2; ++s) {
                const int cs = (s * 4 + quad) ^ rs;
                bf16x8 bh = *(const bf16x8*)(sWh + r * 64 + cs * 8);
                bf16x8 bl = *(const bf16x8*)(sWl + r * 64 + cs * 8);
                acc[ct] = __builtin_amdgcn_mfma_f32_16x16x32_bf16(ahA[s], bh, acc[ct], 0, 0, 0);
                acc[ct] = __builtin_amdgcn_mfma_f32_16x16x32_bf16(alA[s], bh, acc[ct], 0, 0, 0);
                acc[ct] = __builtin_amdgcn_mfma_f32_16x16x32_bf16(ahA[s], bl, acc[ct], 0, 0, 0);
            }
        }
        seg_epilogue(acc, b2v, seg, l16, quad, srcUp,
                     rcA[0], rcA[1], rcA[2], rcA[3],
                     AcL1, AcL2, AcL3, AcT0, AcT1, AcT2,
                     Am1, Am2, Am12, Awhole, AcontNext, Ag1, Ag2, Ag3);
    }

    // ---- strip B: GEMM2 + epilogue -----------------------------------------
    {
        f32x4 acc[8] = {};
        #pragma unroll
        for (int ct = 0; ct < 8; ++ct) {
            const int r = 16 * ct + l16;
            const int rs = r & 7;
            #pragma unroll
            for (int s = 0; s < 2; ++s) {
                const int cs = (s * 4 + quad) ^ rs;
                bf16x8 bh = *(const bf16x8*)(sWh + r * 64 + cs * 8);
                bf16x8 bl = *(const bf16x8*)(sWl + r * 64 + cs * 8);
                acc[ct] = __builtin_amdgcn_mfma_f32_16x16x32_bf16(ahB[s], bh, acc[ct], 0, 0, 0);
                acc[ct] = __builtin_amdgcn_mfma_f32_16x16x32_bf16(alB[s], bh, acc[ct], 0, 0, 0);
                acc[ct] = __builtin_amdgcn_mfma_f32_16x16x32_bf16(ahB[s], bl, acc[ct], 0, 0, 0);
            }
        }
        seg_epilogue(acc, b2v, seg, l16, quad, srcUp,
                     rcB[0], rcB[1], rcB[2], rcB[3],
                     BcL1, BcL2, BcL3, BcT0, BcT1, BcT2,
                     Bm1, Bm2, Bm12, Bwhole, BcontNext, Bg1, Bg2, Bg3);
    }
}

// ---------------------------------------------------------------------------
// tail_kernel: per node: m = seg/cnt ; out = relu(m @ Wd1 + bd1) @ Wd2 + bd2
// ---------------------------------------------------------------------------
__global__ __launch_bounds__(256) void tail_kernel(
    const float* __restrict__ seg, const uint32_t* __restrict__ row_off,
    const float* __restrict__ bd1, const float* __restrict__ Wd2,
    const float* __restrict__ bd2, float* __restrict__ out)
{
    __shared__ __align__(16) __bf16 sAh[64 * 136];
    __shared__ __align__(16) __bf16 sAl[64 * 136];
    __shared__ float sOut[64];
    const int t = threadIdx.x;
    const int w = t >> 6, lane = t & 63, quad = lane >> 4, l16 = lane & 15;
    const int node0 = blockIdx.x * 64;

    if (t < 64) sOut[t] = 0.f;

    {
        const int r = t >> 2, kq = (t & 3) * 32;
        const int node = node0 + r;
        f32x4 v[8];
        if (node < NN) {
            uint32_t c = row_off[node + 1] - row_off[node];
            float inv = (c > 0u) ? 1.0f / (float)c : 0.f;
            const float* p = seg + (size_t)node * 128 + kq;
            #pragma unroll
            for (int i = 0; i < 8; ++i) v[i] = *(const f32x4*)(p + 4 * i) * inv;
        } else {
            #pragma unroll
            for (int i = 0; i < 8; ++i) v[i] = (f32x4){0.f, 0.f, 0.f, 0.f};
        }
        bf16x8 hb[4], lb[4];
        #pragma unroll
        for (int i = 0; i < 8; ++i) {
            #pragma unroll
            for (int j = 0; j < 4; ++j) {
                __bf16 h, l; split1(v[i][j], h, l);
                hb[i >> 1][(i & 1) * 4 + j] = h;
                lb[i >> 1][(i & 1) * 4 + j] = l;
            }
        }
        __bf16* dh = sAh + r * 136 + kq;
        __bf16* dl = sAl + r * 136 + kq;
        #pragma unroll
        for (int i = 0; i < 4; ++i) {
            *(bf16x8*)(dh + 8 * i) = hb[i];
            *(bf16x8*)(dl + 8 * i) = lb[i];
        }
    }
    __syncthreads();

    const int n = 16 * w + l16;
    const __bf16* bhp = g_wd1h + n * 128;
    const __bf16* blp = g_wd1l + n * 128;
    f32x4 acc[4] = {};
    #pragma unroll
    for (int kq = 0; kq < 4; ++kq) {
        const int k0 = kq * 32 + quad * 8;
        bf16x8 bh = *(const bf16x8*)(bhp + k0);
        bf16x8 bl = *(const bf16x8*)(blp + k0);
        #pragma unroll
        for (int st = 0; st < 4; ++st) {
            bf16x8 ah = *(const bf16x8*)(sAh + (16 * st + l16) * 136 + k0);
            bf16x8 al = *(const bf16x8*)(sAl + (16 * st + l16) * 136 + k0);
            acc[st] = __builtin_amdgcn_mfma_f32_16x16x32_bf16(ah, bh, acc[st], 0, 0, 0);
            acc[st] = __builtin_amdgcn_mfma_f32_16x16x32_bf16(al, bh, acc[st], 0, 0, 0);
            acc[st] = __builtin_amdgcn_mfma_f32_16x16x32_bf16(ah, bl, acc[st], 0, 0, 0);
        }
    }

    const float bd1v = bd1[n];
    const float wd2v = Wd2[n];
    #pragma unroll
    for (int st = 0; st < 4; ++st) {
        #pragma unroll
        for (int r = 0; r < 4; ++r) {
            float p = fmaxf(acc[st][r] + bd1v, 0.f) * wd2v;
            p += __shfl_xor(p, 1, 16);
            p += __shfl_xor(p, 2, 16);
            p += __shfl_xor(p, 4, 16);
            p += __shfl_xor(p, 8, 16);
            if (l16 == 0) atomicAdd(&sOut[16 * st + quad * 4 + r], p);
        }
    }
    __syncthreads();
    if (t < 64) {
        const int node = node0 + t;
        if (node < NN) out[node] = sOut[t] + bd2[0];
    }
}

// ---------------------------------------------------------------------------
extern "C" void kernel_launch(void* const* d_in, const int* in_sizes, int n_in,
                              void* d_out, int out_size, void* d_ws, size_t ws_size,
                              hipStream_t stream) {
    const float* x   = (const float*)d_in[0];
    const int*   snd = (const int*)  d_in[1];
    const int*   rcv = (const int*)  d_in[2];
    const float* W1a = (const float*)d_in[3];
    const float* b1a = (const float*)d_in[4];
    const float* W2a = (const float*)d_in[5];
    const float* b2a = (const float*)d_in[6];
    const float* W1b = (const float*)d_in[7];
    const float* b1b = (const float*)d_in[8];
    const float* W2b = (const float*)d_in[9];
    const float* b2b = (const float*)d_in[10];
    const float* Wd1 = (const float*)d_in[11];
    const float* bd1 = (const float*)d_in[12];
    const float* Wd2 = (const float*)d_in[13];
    const float* bd2 = (const float*)d_in[14];
    float* out = (float*)d_out;

    // ws layout: seg [NN*128 f32] | hist [NN] | cursor [NN] | row_off [NN+1] |
    //            pre [NN] | bsum [256] | srt [NE int2] | hrp [NN*64] | hsp [NN*64]
    float*    seg     = (float*)d_ws;
    uint32_t* hist    = (uint32_t*)(seg + (size_t)NN * 128);
    uint32_t* cursor  = hist + NN;
    uint32_t* row_off = cursor + NN;
    uint32_t* pre     = row_off + (NN + 1);
    uint32_t* bsum    = pre + NN;
    int2*     srt     = (int2*)(bsum + 256);
    float*    hrp     = (float*)(srt + NE);
    float*    hsp     = hrp + (size_t)NN * 64;

    hipMemsetAsync(seg, 0, ((size_t)NN * 128 + 2 * NN) * sizeof(float), stream);

    const int nb  = (NN + 255) / 256;   // 196
    const int nbn = (NN + 63) / 64;     // 782
    const int neb = (NE + 255) / 256;   // 3125

    hipLaunchKernelGGL(pre_kernel, dim3(224 + neb), dim3(256), 0, stream,
                       W1a, W2a, W1b, W2b, Wd1, rcv, hist);
    hipLaunchKernelGGL(scan1_kernel, dim3(nb), dim3(256), 0, stream, hist, pre, bsum);
    hipLaunchKernelGGL(scan2_kernel, dim3(1), dim3(256), 0, stream, bsum, nb);
    hipLaunchKernelGGL(scan3_kernel, dim3(nb), dim3(256), 0, stream, pre, bsum, row_off);
    hipLaunchKernelGGL(mid_kernel, dim3(nbn + neb), dim3(256), 0, stream,
                       x, b1a, hrp, hsp, rcv, snd, row_off, cursor, srt, nbn);

    // layer 1 edges
    hipLaunchKernelGGL(edge_gemm2_kernel, dim3(NE / 128), dim3(256), 0, stream,
                       hrp, hsp, srt, b2a, seg, 0);
    // layer 2 node half-products (mean-mode; rezeros seg)
    hipLaunchKernelGGL(node_w1_kernel, dim3(nbn), dim3(256), 0, stream,
                       seg, row_off, seg, b1b, hrp, hsp, 1);
    // layer 2 edges
    hipLaunchKernelGGL(edge_gemm2_kernel, dim3(NE / 128), dim3(256), 0, stream,
                       hrp, hsp, srt, b2b, seg, 1);
    // dense tail
    hipLaunchKernelGGL(tail_kernel, dim3(nbn), dim3(256), 0, stream,
                       seg, row_off, bd1, Wd2, bd2, out);
}

// Round 14
// 392.072 us; speedup vs baseline: 1.6849x; 1.0193x over previous
//
#include <hip/hip_runtime.h>
#include <hip/hip_bf16.h>
#include <cstdint>
#include <cstddef>

#define NN 50000
#define NE 800000

typedef __bf16 bf16x8 __attribute__((ext_vector_type(8)));
typedef float  f32x4  __attribute__((ext_vector_type(4)));

// Pre-split, pre-transposed weights (hi/lo bf16 planes).
// W1t: [n][k] n<64,k<256 ; W2t: [n][k] n<128,k<64 ; Wd1t: [n][k] n<64,k<128.
__device__ __bf16 g_w1h[2][64 * 256];
__device__ __bf16 g_w1l[2][64 * 256];
__device__ __bf16 g_w2h[2][128 * 64];
__device__ __bf16 g_w2l[2][128 * 64];
__device__ __bf16 g_wd1h[64 * 128];
__device__ __bf16 g_wd1l[64 * 128];

__device__ __forceinline__ void split1(float v, __bf16& h, __bf16& l) {
    h = (__bf16)v;
    l = (__bf16)(v - (float)h);
}

// ---------------------------------------------------------------------------
// pre_kernel: blocks [0,224) split weights; blocks [224,224+3125) histogram
// ---------------------------------------------------------------------------
__global__ __launch_bounds__(256) void pre_kernel(
    const float* __restrict__ W1a, const float* __restrict__ W2a,
    const float* __restrict__ W1b, const float* __restrict__ W2b,
    const float* __restrict__ Wd1,
    const int* __restrict__ rcv, uint32_t* __restrict__ hist)
{
    const int b = blockIdx.x, t = threadIdx.x;
    if (b < 224) {
        int tid = b * 256 + t;
        if (tid < 16384) {                 // W1a [256][64] -> [64][256]
            int k = tid >> 6, n = tid & 63;
            __bf16 h, l; split1(W1a[tid], h, l);
            g_w1h[0][n * 256 + k] = h; g_w1l[0][n * 256 + k] = l;
        } else if (tid < 24576) {          // W2a [64][128] -> [128][64]
            int i = tid - 16384; int k = i >> 7, n = i & 127;
            __bf16 h, l; split1(W2a[i], h, l);
            g_w2h[0][n * 64 + k] = h; g_w2l[0][n * 64 + k] = l;
        } else if (tid < 40960) {          // W1b
            int i = tid - 24576; int k = i >> 6, n = i & 63;
            __bf16 h, l; split1(W1b[i], h, l);
            g_w1h[1][n * 256 + k] = h; g_w1l[1][n * 256 + k] = l;
        } else if (tid < 49152) {          // W2b
            int i = tid - 40960; int k = i >> 7, n = i & 127;
            __bf16 h, l; split1(W2b[i], h, l);
            g_w2h[1][n * 64 + k] = h; g_w2l[1][n * 64 + k] = l;
        } else if (tid < 57344) {          // Wd1 [128][64] -> [64][128]
            int i = tid - 49152; int k = i >> 6, n = i & 63;
            __bf16 h, l; split1(Wd1[i], h, l);
            g_wd1h[n * 128 + k] = h; g_wd1l[n * 128 + k] = l;
        }
    } else {
        int e = (b - 224) * 256 + t;
        if (e < NE) atomicAdd(hist + rcv[e], 1u);
    }
}

// ---------------------------------------------------------------------------
// counting-sort scan: scan1 = per-256-chunk exclusive scan + chunk totals;
// scan23 = row_off[i] = pre[i] + sum(bsum[0..chunk)) (scan2 folded in).
// ---------------------------------------------------------------------------
__global__ void scan1_kernel(const uint32_t* __restrict__ hist,
                             uint32_t* __restrict__ pre, uint32_t* __restrict__ bsum) {
    __shared__ uint32_t s[256];
    int t = threadIdx.x;
    int i = blockIdx.x * 256 + t;
    uint32_t v = (i < NN) ? hist[i] : 0u;
    s[t] = v; __syncthreads();
    #pragma unroll
    for (int off = 1; off < 256; off <<= 1) {
        uint32_t tv = (t >= off) ? s[t - off] : 0u;
        __syncthreads();
        s[t] += tv; __syncthreads();
    }
    if (i < NN) pre[i] = s[t] - v;
    if (t == 255) bsum[blockIdx.x] = s[255];
}

__global__ void scan23_kernel(const uint32_t* __restrict__ pre,
                              const uint32_t* __restrict__ bsum,
                              uint32_t* __restrict__ row_off) {
    __shared__ uint32_t s[256];
    const int b = blockIdx.x, t = threadIdx.x;
    uint32_t v = (t < b) ? bsum[t] : 0u;     // b <= 195 < 256
    s[t] = v; __syncthreads();
    #pragma unroll
    for (int off = 128; off > 0; off >>= 1) {
        if (t < off) s[t] += s[t + off];
        __syncthreads();
    }
    const uint32_t base = s[0];
    int i = b * 256 + t;
    if (i < NN) row_off[i] = pre[i] + base;
    if (i == 0) row_off[NN] = NE;
}

// ---------------------------------------------------------------------------
// node_w1_body: per-node half-products of GEMM1.
//   hrp[n] = src[n] @ W1_top + b1 ; hsp[n] = src[n] @ W1_bot
// mean-mode (row_off != null): scale by 1/cnt and rezero seg.
// ---------------------------------------------------------------------------
__device__ __forceinline__ void node_w1_body(
    const float* __restrict__ src, const uint32_t* __restrict__ row_off,
    float* __restrict__ seg_rz, const float* __restrict__ b1,
    float* __restrict__ hrp, float* __restrict__ hsp, int layer, int blk)
{
    __shared__ __align__(16) __bf16 sAh[64 * 136];
    __shared__ __align__(16) __bf16 sAl[64 * 136];
    const int t = threadIdx.x;
    const int w = t >> 6, lane = t & 63, quad = lane >> 4, l16 = lane & 15;
    const int node0 = blk * 64;

    {
        const int r = t >> 2, kq = (t & 3) * 32;
        const int node = node0 + r;
        f32x4 v[8];
        if (node < NN) {
            const float* p = src + (size_t)node * 128 + kq;
            #pragma unroll
            for (int i = 0; i < 8; ++i) v[i] = *(const f32x4*)(p + 4 * i);
            if (row_off) {
                uint32_t c = row_off[node + 1] - row_off[node];
                float inv = (c > 0u) ? 1.0f / (float)c : 0.f;
                #pragma unroll
                for (int i = 0; i < 8; ++i) v[i] = v[i] * inv;
                float* z = seg_rz + (size_t)node * 128 + kq;
                #pragma unroll
                for (int i = 0; i < 8; ++i) *(f32x4*)(z + 4 * i) = (f32x4){0.f, 0.f, 0.f, 0.f};
            }
        } else {
            #pragma unroll
            for (int i = 0; i < 8; ++i) v[i] = (f32x4){0.f, 0.f, 0.f, 0.f};
        }
        bf16x8 hb[4], lb[4];
        #pragma unroll
        for (int i = 0; i < 8; ++i) {
            #pragma unroll
            for (int j = 0; j < 4; ++j) {
                __bf16 h, l; split1(v[i][j], h, l);
                hb[i >> 1][(i & 1) * 4 + j] = h;
                lb[i >> 1][(i & 1) * 4 + j] = l;
            }
        }
        __bf16* dh = sAh + r * 136 + kq;
        __bf16* dl = sAl + r * 136 + kq;
        #pragma unroll
        for (int i = 0; i < 4; ++i) {
            *(bf16x8*)(dh + 8 * i) = hb[i];
            *(bf16x8*)(dl + 8 * i) = lb[i];
        }
    }
    __syncthreads();

    const int n = 16 * w + l16;
    const __bf16* w1hp = g_w1h[layer] + n * 256;
    const __bf16* w1lp = g_w1l[layer] + n * 256;
    f32x4 acc[4][2] = {};
    #pragma unroll
    for (int kq = 0; kq < 4; ++kq) {
        const int k0 = kq * 32 + quad * 8;
        bf16x8 bh0 = *(const bf16x8*)(w1hp + k0);
        bf16x8 bl0 = *(const bf16x8*)(w1lp + k0);
        bf16x8 bh1 = *(const bf16x8*)(w1hp + 128 + k0);
        bf16x8 bl1 = *(const bf16x8*)(w1lp + 128 + k0);
        #pragma unroll
        for (int st = 0; st < 4; ++st) {
            bf16x8 ah = *(const bf16x8*)(sAh + (16 * st + l16) * 136 + k0);
            bf16x8 al = *(const bf16x8*)(sAl + (16 * st + l16) * 136 + k0);
            acc[st][0] = __builtin_amdgcn_mfma_f32_16x16x32_bf16(ah, bh0, acc[st][0], 0, 0, 0);
            acc[st][0] = __builtin_amdgcn_mfma_f32_16x16x32_bf16(al, bh0, acc[st][0], 0, 0, 0);
            acc[st][0] = __builtin_amdgcn_mfma_f32_16x16x32_bf16(ah, bl0, acc[st][0], 0, 0, 0);
            acc[st][1] = __builtin_amdgcn_mfma_f32_16x16x32_bf16(ah, bh1, acc[st][1], 0, 0, 0);
            acc[st][1] = __builtin_amdgcn_mfma_f32_16x16x32_bf16(al, bh1, acc[st][1], 0, 0, 0);
            acc[st][1] = __builtin_amdgcn_mfma_f32_16x16x32_bf16(ah, bl1, acc[st][1], 0, 0, 0);
        }
    }

    const float b1v = b1[n];
    #pragma unroll
    for (int st = 0; st < 4; ++st) {
        #pragma unroll
        for (int r = 0; r < 4; ++r) {
            const int node = node0 + 16 * st + quad * 4 + r;
            if (node < NN) {
                hrp[(size_t)node * 64 + n] = acc[st][0][r] + b1v;
                hsp[(size_t)node * 64 + n] = acc[st][1][r];
            }
        }
    }
}

// standalone node_w1 (layer-2 mean mode)
__global__ __launch_bounds__(256) void node_w1_kernel(
    const float* __restrict__ src, const uint32_t* __restrict__ row_off,
    float* __restrict__ seg_rz, const float* __restrict__ b1,
    float* __restrict__ hrp, float* __restrict__ hsp, int layer)
{
    node_w1_body(src, row_off, seg_rz, b1, hrp, hsp, layer, blockIdx.x);
}

// ---------------------------------------------------------------------------
// mid_kernel: blocks [0,nbn) = node_w1 layer-0; rest = rank-scatter building
// sorted (recv,send) pairs.
// ---------------------------------------------------------------------------
__global__ __launch_bounds__(256) void mid_kernel(
    const float* __restrict__ x, const float* __restrict__ b1a,
    float* __restrict__ hrp, float* __restrict__ hsp,
    const int* __restrict__ rcv, const int* __restrict__ snd,
    const uint32_t* __restrict__ row_off, uint32_t* __restrict__ cursor,
    int2* __restrict__ srt, int nbn)
{
    if ((int)blockIdx.x < nbn) {
        node_w1_body(x, (const uint32_t*)nullptr, (float*)nullptr, b1a, hrp, hsp, 0,
                     blockIdx.x);
    } else {
        int e = (blockIdx.x - nbn) * 256 + threadIdx.x;
        if (e < NE) {
            int r = rcv[e];
            uint32_t k = atomicAdd(cursor + r, 1u);
            srt[row_off[r] + k] = make_int2(r, snd[e]);
        }
    }
}

// ---------------------------------------------------------------------------
// seg_epilogue: exact segmented reduction over one sorted 16-edge strip.
// One atomic per receiver-run.
// ---------------------------------------------------------------------------
__device__ __forceinline__ void seg_epilogue(
    const f32x4* __restrict__ acc, const float* __restrict__ b2v,
    float* __restrict__ seg, int l16, int quad, int srcUp,
    int rc0, int rc1, int rc2, int rc3,
    float cL1, float cL2, float cL3, float cT0, float cT1, float cT2,
    bool m1, bool m2, bool m12same, bool whole, bool contNext,
    bool g1, bool g2, bool g3)
{
    #pragma unroll
    for (int ct = 0; ct < 8; ++ct) {
        const int n = 16 * ct + l16;
        const float bv = b2v[ct];
        const float v0 = fmaxf(acc[ct][0] + bv, 0.f);
        const float v1 = fmaxf(acc[ct][1] + bv, 0.f);
        const float v2 = fmaxf(acc[ct][2] + bv, 0.f);
        const float v3 = fmaxf(acc[ct][3] + bv, 0.f);

        float L = fmaf(cL3, v3, fmaf(cL2, v2, fmaf(cL1, v1, v0)));
        float T = fmaf(cT0, v0, fmaf(cT1, v1, fmaf(cT2, v2, v3)));

        if (m12same) {
            atomicAdd(seg + (size_t)rc1 * 128 + n, v1 + v2);
        } else {
            if (m1) atomicAdd(seg + (size_t)rc1 * 128 + n, v1);
            if (m2) atomicAdd(seg + (size_t)rc2 * 128 + n, v2);
        }

        float Tf = T, Lc = L;
        {
            float Tup = __shfl(Tf, srcUp);
            float add = g1 ? Tup : 0.f;
            if (whole) Tf += add; else Lc += add;
        }
        {
            float Tup = __shfl(Tf, srcUp);
            float add = g2 ? Tup : 0.f;
            if (whole) Tf += add; else Lc += add;
        }
        {
            float Tup = __shfl(Tf, srcUp);
            float add = g3 ? Tup : 0.f;
            if (whole) Tf += add; else Lc += add;
        }

        if (!whole)    atomicAdd(seg + (size_t)rc0 * 128 + n, Lc);
        if (!contNext) atomicAdd(seg + (size_t)rc3 * 128 + n, Tf);
    }
}

// ---------------------------------------------------------------------------
// edge_gemm2_kernel: 128 sorted edges/block, 4 waves; wave w owns TWO 16-edge
// strips and ALL 128 output cols. W2 staged in LDS with XOR-swizzled 16B
// chunks at stride 64 (no pad): chunk c of row r stored at c^(r&7).
// LDS = 32768 B -> 5 blocks/CU; plain launch_bounds (round 11's forced
// (256,5) squeezed VGPR 68->48 and spilled: WRITE 48->554 MB).
// ---------------------------------------------------------------------------
__global__ __launch_bounds__(256) void edge_gemm2_kernel(
    const float* __restrict__ hrp, const float* __restrict__ hsp,
    const int2* __restrict__ srt,
    const float* __restrict__ b2,
    float* __restrict__ seg, int layer)
{
    __shared__ __align__(16) __bf16 sWh[128 * 64];
    __shared__ __align__(16) __bf16 sWl[128 * 64];

    const int t = threadIdx.x;
    const int w = t >> 6, lane = t & 63, quad = lane >> 4, l16 = lane & 15;
    const int srcUp = (lane >= 16) ? lane - 16 : lane;
    const int srcDn = (lane < 48) ? lane + 16 : lane;

    // ---- stage W2 planes, swizzled (thread t -> row t>>1, half t&1) --------
    {
        const int r = t >> 1, hh = t & 1;
        const __bf16* sh = g_w2h[layer] + r * 64 + hh * 32;
        const __bf16* sl = g_w2l[layer] + r * 64 + hh * 32;
        __bf16* dh = sWh + r * 64;
        __bf16* dl = sWl + r * 64;
        const int rs = r & 7;
        #pragma unroll
        for (int i = 0; i < 4; ++i) {
            const int c = hh * 4 + i;           // source chunk index 0..7
            const int cs = c ^ rs;              // swizzled slot
            *(bf16x8*)(dh + cs * 8) = *(const bf16x8*)(sh + 8 * i);
            *(bf16x8*)(dl + cs * 8) = *(const bf16x8*)(sl + 8 * i);
        }
    }

    // ---- issue both strips' gathers (independent) --------------------------
    const int eA = blockIdx.x * 128 + w * 16;
    const int2 rsA = srt[eA + l16];
    const int2 rsB = srt[eA + 64 + l16];

    const float* hpA = hrp + (size_t)rsA.x * 64 + quad * 8;
    const float* spA = hsp + (size_t)rsA.y * 64 + quad * 8;
    const float* hpB = hrp + (size_t)rsB.x * 64 + quad * 8;
    const float* spB = hsp + (size_t)rsB.y * 64 + quad * 8;

    f32x4 ga0[4], gb0[4], ga1[4], gb1[4];
    ga0[0] = *(const f32x4*)(hpA);      ga0[1] = *(const f32x4*)(hpA + 4);
    ga0[2] = *(const f32x4*)(hpA + 32); ga0[3] = *(const f32x4*)(hpA + 36);
    gb0[0] = *(const f32x4*)(spA);      gb0[1] = *(const f32x4*)(spA + 4);
    gb0[2] = *(const f32x4*)(spA + 32); gb0[3] = *(const f32x4*)(spA + 36);
    ga1[0] = *(const f32x4*)(hpB);      ga1[1] = *(const f32x4*)(hpB + 4);
    ga1[2] = *(const f32x4*)(hpB + 32); ga1[3] = *(const f32x4*)(hpB + 36);
    gb1[0] = *(const f32x4*)(spB);      gb1[1] = *(const f32x4*)(spB + 4);
    gb1[2] = *(const f32x4*)(spB + 32); gb1[3] = *(const f32x4*)(spB + 36);

    float b2v[8];
    #pragma unroll
    for (int ct = 0; ct < 8; ++ct) b2v[ct] = b2[16 * ct + l16];

    // ---- pack A-fragments: h = relu(hrp+hsp), split hi/lo ------------------
    bf16x8 ahA[2], alA[2], ahB[2], alB[2];
    #pragma unroll
    for (int s = 0; s < 2; ++s) {
        #pragma unroll
        for (int hh = 0; hh < 2; ++hh) {
            f32x4 av = ga0[s * 2 + hh], bv = gb0[s * 2 + hh];
            f32x4 aw = ga1[s * 2 + hh], bw = gb1[s * 2 + hh];
            #pragma unroll
            for (int j = 0; j < 4; ++j) {
                float vA = fmaxf(av[j] + bv[j], 0.f);
                float vB = fmaxf(aw[j] + bw[j], 0.f);
                __bf16 h, l;
                split1(vA, h, l); ahA[s][hh * 4 + j] = h; alA[s][hh * 4 + j] = l;
                split1(vB, h, l); ahB[s][hh * 4 + j] = h; alB[s][hh * 4 + j] = l;
            }
        }
    }

    // ---- structural receiver masks per strip -------------------------------
    int rcA[4], rcB[4];
    #pragma unroll
    for (int r = 0; r < 4; ++r) {
        rcA[r] = __shfl(rsA.x, quad * 4 + r, 16);
        rcB[r] = __shfl(rsB.x, quad * 4 + r, 16);
    }

    const bool A10 = (rcA[1] == rcA[0]), A20 = (rcA[2] == rcA[0]);
    const bool A30 = (rcA[3] == rcA[0]), A23 = (rcA[2] == rcA[3]);
    const bool A13 = (rcA[1] == rcA[3]);
    const bool Awhole = A30;
    const int  ArUp = __shfl(rcA[3], srcUp);
    const int  ArDn = __shfl(rcA[0], srcDn);
    const bool AmatchUp  = (quad > 0) && (ArUp == rcA[0]);
    const bool AcontNext = (quad < 3) && (ArDn == rcA[3]);
    const bool Am1 = !A10 && !A13, Am2 = !A20 && !A23;
    const bool Am12 = Am1 && Am2 && (rcA[1] == rcA[2]);
    const float AcL1 = A10 ? 1.f : 0.f, AcL2 = A20 ? 1.f : 0.f, AcL3 = A30 ? 1.f : 0.f;
    const float AcT2 = A23 ? 1.f : 0.f, AcT1 = A13 ? 1.f : 0.f, AcT0 = A30 ? 1.f : 0.f;
    const bool Ag1 = AmatchUp && (quad == 1), Ag2 = AmatchUp && (quad == 2),
               Ag3 = AmatchUp && (quad == 3);

    const bool B10 = (rcB[1] == rcB[0]), B20 = (rcB[2] == rcB[0]);
    const bool B30 = (rcB[3] == rcB[0]), B23 = (rcB[2] == rcB[3]);
    const bool B13 = (rcB[1] == rcB[3]);
    const bool Bwhole = B30;
    const int  BrUp = __shfl(rcB[3], srcUp);
    const int  BrDn = __shfl(rcB[0], srcDn);
    const bool BmatchUp  = (quad > 0) && (BrUp == rcB[0]);
    const bool BcontNext = (quad < 3) && (BrDn == rcB[3]);
    const bool Bm1 = !B10 && !B13, Bm2 = !B20 && !B23;
    const bool Bm12 = Bm1 && Bm2 && (rcB[1] == rcB[2]);
    const float BcL1 = B10 ? 1.f : 0.f, BcL2 = B20 ? 1.f : 0.f, BcL3 = B30 ? 1.f : 0.f;
    const float BcT2 = B23 ? 1.f : 0.f, BcT1 = B13 ? 1.f : 0.f, BcT0 = B30 ? 1.f : 0.f;
    const bool Bg1 = BmatchUp && (quad == 1), Bg2 = BmatchUp && (quad == 2),
               Bg3 = BmatchUp && (quad == 3);

    __syncthreads();   // weights staged

    // ---- strip A: GEMM2 + epilogue -----------------------------------------
    {
        f32x4 acc[8] = {};
        #pragma unroll
        for (int ct = 0; ct < 8; ++ct) {
            const int r = 16 * ct + l16;
            const int rs = r & 7;
            #pragma unroll
            for (int s = 0; s < 2; ++s) {
                const int cs = (s * 4 + quad) ^ rs;
                bf16x8 bh = *(const bf16x8*)(sWh + r * 64 + cs * 8);
                bf16x8 bl = *(const bf16x8*)(sWl + r * 64 + cs * 8);
                acc[ct] = __builtin_amdgcn_mfma_f32_16x16x32_bf16(ahA[s], bh, acc[ct], 0, 0, 0);
                acc[ct] = __builtin_amdgcn_mfma_f32_16x16x32_bf16(alA[s], bh, acc[ct], 0, 0, 0);
                acc[ct] = __builtin_amdgcn_mfma_f32_16x16x32_bf16(ahA[s], bl, acc[ct], 0, 0, 0);
            }
        }
        seg_epilogue(acc, b2v, seg, l16, quad, srcUp,
                     rcA[0], rcA[1], rcA[2], rcA[3],
                     AcL1, AcL2, AcL3, AcT0, AcT1, AcT2,
                     Am1, Am2, Am12, Awhole, AcontNext, Ag1, Ag2, Ag3);
    }

    // ---- strip B: GEMM2 + epilogue -----------------------------------------
    {
        f32x4 acc[8] = {};
        #pragma unroll
        for (int ct = 0; ct < 8; ++ct) {
            const int r = 16 * ct + l16;
            const int rs = r & 7;
            #pragma unroll
            for (int s = 0; s < 2; ++s) {
                const int cs = (s * 4 + quad) ^ rs;
                bf16x8 bh = *(const bf16x8*)(sWh + r * 64 + cs * 8);
                bf16x8 bl = *(const bf16x8*)(sWl + r * 64 + cs * 8);
                acc[ct] = __builtin_amdgcn_mfma_f32_16x16x32_bf16(ahB[s], bh, acc[ct], 0, 0, 0);
                acc[ct] = __builtin_amdgcn_mfma_f32_16x16x32_bf16(alB[s], bh, acc[ct], 0, 0, 0);
                acc[ct] = __builtin_amdgcn_mfma_f32_16x16x32_bf16(ahB[s], bl, acc[ct], 0, 0, 0);
            }
        }
        seg_epilogue(acc, b2v, seg, l16, quad, srcUp,
                     rcB[0], rcB[1], rcB[2], rcB[3],
                     BcL1, BcL2, BcL3, BcT0, BcT1, BcT2,
                     Bm1, Bm2, Bm12, Bwhole, BcontNext, Bg1, Bg2, Bg3);
    }
}

// ---------------------------------------------------------------------------
// tail_kernel: per node: m = seg/cnt ; out = relu(m @ Wd1 + bd1) @ Wd2 + bd2
// ---------------------------------------------------------------------------
__global__ __launch_bounds__(256) void tail_kernel(
    const float* __restrict__ seg, const uint32_t* __restrict__ row_off,
    const float* __restrict__ bd1, const float* __restrict__ Wd2,
    const float* __restrict__ bd2, float* __restrict__ out)
{
    __shared__ __align__(16) __bf16 sAh[64 * 136];
    __shared__ __align__(16) __bf16 sAl[64 * 136];
    __shared__ float sOut[64];
    const int t = threadIdx.x;
    const int w = t >> 6, lane = t & 63, quad = lane >> 4, l16 = lane & 15;
    const int node0 = blockIdx.x * 64;

    if (t < 64) sOut[t] = 0.f;

    {
        const int r = t >> 2, kq = (t & 3) * 32;
        const int node = node0 + r;
        f32x4 v[8];
        if (node < NN) {
            uint32_t c = row_off[node + 1] - row_off[node];
            float inv = (c > 0u) ? 1.0f / (float)c : 0.f;
            const float* p = seg + (size_t)node * 128 + kq;
            #pragma unroll
            for (int i = 0; i < 8; ++i) v[i] = *(const f32x4*)(p + 4 * i) * inv;
        } else {
            #pragma unroll
            for (int i = 0; i < 8; ++i) v[i] = (f32x4){0.f, 0.f, 0.f, 0.f};
        }
        bf16x8 hb[4], lb[4];
        #pragma unroll
        for (int i = 0; i < 8; ++i) {
            #pragma unroll
            for (int j = 0; j < 4; ++j) {
                __bf16 h, l; split1(v[i][j], h, l);
                hb[i >> 1][(i & 1) * 4 + j] = h;
                lb[i >> 1][(i & 1) * 4 + j] = l;
            }
        }
        __bf16* dh = sAh + r * 136 + kq;
        __bf16* dl = sAl + r * 136 + kq;
        #pragma unroll
        for (int i = 0; i < 4; ++i) {
            *(bf16x8*)(dh + 8 * i) = hb[i];
            *(bf16x8*)(dl + 8 * i) = lb[i];
        }
    }
    __syncthreads();

    const int n = 16 * w + l16;
    const __bf16* bhp = g_wd1h + n * 128;
    const __bf16* blp = g_wd1l + n * 128;
    f32x4 acc[4] = {};
    #pragma unroll
    for (int kq = 0; kq < 4; ++kq) {
        const int k0 = kq * 32 + quad * 8;
        bf16x8 bh = *(const bf16x8*)(bhp + k0);
        bf16x8 bl = *(const bf16x8*)(blp + k0);
        #pragma unroll
        for (int st = 0; st < 4; ++st) {
            bf16x8 ah = *(const bf16x8*)(sAh + (16 * st + l16) * 136 + k0);
            bf16x8 al = *(const bf16x8*)(sAl + (16 * st + l16) * 136 + k0);
            acc[st] = __builtin_amdgcn_mfma_f32_16x16x32_bf16(ah, bh, acc[st], 0, 0, 0);
            acc[st] = __builtin_amdgcn_mfma_f32_16x16x32_bf16(al, bh, acc[st], 0, 0, 0);
            acc[st] = __builtin_amdgcn_mfma_f32_16x16x32_bf16(ah, bl, acc[st], 0, 0, 0);
        }
    }

    const float bd1v = bd1[n];
    const float wd2v = Wd2[n];
    #pragma unroll
    for (int st = 0; st < 4; ++st) {
        #pragma unroll
        for (int r = 0; r < 4; ++r) {
            float p = fmaxf(acc[st][r] + bd1v, 0.f) * wd2v;
            p += __shfl_xor(p, 1, 16);
            p += __shfl_xor(p, 2, 16);
            p += __shfl_xor(p, 4, 16);
            p += __shfl_xor(p, 8, 16);
            if (l16 == 0) atomicAdd(&sOut[16 * st + quad * 4 + r], p);
        }
    }
    __syncthreads();
    if (t < 64) {
        const int node = node0 + t;
        if (node < NN) out[node] = sOut[t] + bd2[0];
    }
}

// ---------------------------------------------------------------------------
extern "C" void kernel_launch(void* const* d_in, const int* in_sizes, int n_in,
                              void* d_out, int out_size, void* d_ws, size_t ws_size,
                              hipStream_t stream) {
    const float* x   = (const float*)d_in[0];
    const int*   snd = (const int*)  d_in[1];
    const int*   rcv = (const int*)  d_in[2];
    const float* W1a = (const float*)d_in[3];
    const float* b1a = (const float*)d_in[4];
    const float* W2a = (const float*)d_in[5];
    const float* b2a = (const float*)d_in[6];
    const float* W1b = (const float*)d_in[7];
    const float* b1b = (const float*)d_in[8];
    const float* W2b = (const float*)d_in[9];
    const float* b2b = (const float*)d_in[10];
    const float* Wd1 = (const float*)d_in[11];
    const float* bd1 = (const float*)d_in[12];
    const float* Wd2 = (const float*)d_in[13];
    const float* bd2 = (const float*)d_in[14];
    float* out = (float*)d_out;

    // ws layout: seg [NN*128 f32] | hist [NN] | cursor [NN] | row_off [NN+1] |
    //            pre [NN] | bsum [256] | srt [NE int2] | hrp [NN*64] | hsp [NN*64]
    float*    seg     = (float*)d_ws;
    uint32_t* hist    = (uint32_t*)(seg + (size_t)NN * 128);
    uint32_t* cursor  = hist + NN;
    uint32_t* row_off = cursor + NN;
    uint32_t* pre     = row_off + (NN + 1);
    uint32_t* bsum    = pre + NN;
    int2*     srt     = (int2*)(bsum + 256);
    float*    hrp     = (float*)(srt + NE);
    float*    hsp     = hrp + (size_t)NN * 64;

    hipMemsetAsync(seg, 0, ((size_t)NN * 128 + 2 * NN) * sizeof(float), stream);

    const int nb  = (NN + 255) / 256;   // 196
    const int nbn = (NN + 63) / 64;     // 782
    const int neb = (NE + 255) / 256;   // 3125

    hipLaunchKernelGGL(pre_kernel, dim3(224 + neb), dim3(256), 0, stream,
                       W1a, W2a, W1b, W2b, Wd1, rcv, hist);
    hipLaunchKernelGGL(scan1_kernel, dim3(nb), dim3(256), 0, stream, hist, pre, bsum);
    hipLaunchKernelGGL(scan23_kernel, dim3(nb), dim3(256), 0, stream, pre, bsum, row_off);
    hipLaunchKernelGGL(mid_kernel, dim3(nbn + neb), dim3(256), 0, stream,
                       x, b1a, hrp, hsp, rcv, snd, row_off, cursor, srt, nbn);

    // layer 1 edges
    hipLaunchKernelGGL(edge_gemm2_kernel, dim3(NE / 128), dim3(256), 0, stream,
                       hrp, hsp, srt, b2a, seg, 0);
    // layer 2 node half-products (mean-mode; rezeros seg)
    hipLaunchKernelGGL(node_w1_kernel, dim3(nbn), dim3(256), 0, stream,
                       seg, row_off, seg, b1b, hrp, hsp, 1);
    // layer 2 edges
    hipLaunchKernelGGL(edge_gemm2_kernel, dim3(NE / 128), dim3(256), 0, stream,
                       hrp, hsp, srt, b2b, seg, 1);
    // dense tail
    hipLaunchKernelGGL(tail_kernel, dim3(nbn), dim3(256), 0, stream,
                       seg, row_off, bd1, Wd2, bd2, out);
}